// Round 1
// baseline (316.861 us; speedup 1.0000x reference)
//
#include <hip/hip_runtime.h>

// GAE backward scan: gae[t] = delta[t] + coef[t]*gae[t+1], gae[T] = 0
//   delta[t] = reward[t] + GAMMA*next_value[t]*not_done[t] - value[t]
//   coef[t]  = GAMMA*LMBDA*not_done[t]
// advantages = gae; returns = gae + value.
// Parallelized as an associative scan over affine maps f(x) = A + P*x.

#define GAMMA 0.99f
#define LMBDA 0.95f

constexpr int T_LEN     = 2048;
constexpr int PER_THREAD = 8;                 // time steps per thread
constexpr int BLOCK      = T_LEN / PER_THREAD; // 256 threads

__global__ __launch_bounds__(BLOCK) void gae_kernel(
    const float* __restrict__ reward,
    const int*   __restrict__ terminated,
    const float* __restrict__ value,
    const float* __restrict__ next_value,
    float* __restrict__ adv_out,
    float* __restrict__ ret_out)
{
    const int b   = blockIdx.x;
    const int j   = threadIdx.x;
    const size_t base = (size_t)b * T_LEN + (size_t)j * PER_THREAD;

    // ---- coalesced vector loads: each thread owns 8 contiguous time steps
    const float4* r4  = (const float4*)(reward     + base);
    const float4* v4  = (const float4*)(value      + base);
    const float4* n4  = (const float4*)(next_value + base);
    const int4*   t4  = (const int4*)  (terminated + base);

    float4 r0 = r4[0], r1 = r4[1];
    float4 v0 = v4[0], v1 = v4[1];
    float4 n0 = n4[0], n1 = n4[1];
    int4   tA = t4[0], tB = t4[1];

    float rr[8] = {r0.x, r0.y, r0.z, r0.w, r1.x, r1.y, r1.z, r1.w};
    float vv[8] = {v0.x, v0.y, v0.z, v0.w, v1.x, v1.y, v1.z, v1.w};
    float nn[8] = {n0.x, n0.y, n0.z, n0.w, n1.x, n1.y, n1.z, n1.w};
    int   tt[8] = {tA.x, tA.y, tA.z, tA.w, tB.x, tB.y, tB.z, tB.w};

    float delta[8], coef[8];
#pragma unroll
    for (int i = 0; i < 8; ++i) {
        float nd = tt[i] ? 0.0f : 1.0f;
        delta[i] = rr[i] + GAMMA * nn[i] * nd - vv[i];
        coef[i]  = (GAMMA * LMBDA) * nd;
    }

    // ---- per-thread chunk summary: gae_at_chunk_start = A + P * gae_in_from_right
    float A = 0.0f, P = 1.0f;
#pragma unroll
    for (int i = 7; i >= 0; --i) {
        A = delta[i] + coef[i] * A;
        P = coef[i] * P;
    }

    // ---- wave-level backward inclusive scan (affine composition, 6 shfl steps)
    const int lane = j & 63;
    const int wave = j >> 6;
    float SA = A, SP = P;
#pragma unroll
    for (int o = 1; o < 64; o <<= 1) {
        float A2 = __shfl_down(SA, o, 64);
        float P2 = __shfl_down(SP, o, 64);
        if (lane + o < 64) {          // lanes past the end contribute identity
            SA = SA + SP * A2;
            SP = SP * P2;
        }
    }
    // exclusive-from-right: what enters this thread from lane+1
    float EA = __shfl_down(SA, 1, 64);
    float EP = __shfl_down(SP, 1, 64);
    if (lane == 63) { EA = 0.0f; EP = 1.0f; }

    // ---- combine the 4 wave summaries through LDS
    __shared__ float wA[BLOCK / 64];
    __shared__ float wP[BLOCK / 64];
    if (lane == 0) { wA[wave] = SA; wP[wave] = SP; }
    __syncthreads();

    // gae entering this wave from the right = (W_{wave+1} o ... o W_3)(0)
    float accA = 0.0f;
    for (int ww = (BLOCK / 64) - 1; ww > wave; --ww) {
        accA = wA[ww] + wP[ww] * accA;
    }

    // gae entering this thread from the right
    float g = EA + EP * accA;

    // ---- replay the chunk with the true incoming gae; write outputs
    float adv[8];
#pragma unroll
    for (int i = 7; i >= 0; --i) {
        g = delta[i] + coef[i] * g;
        adv[i] = g;
    }

    float4 a0 = {adv[0], adv[1], adv[2], adv[3]};
    float4 a1 = {adv[4], adv[5], adv[6], adv[7]};
    float4 q0 = {adv[0] + vv[0], adv[1] + vv[1], adv[2] + vv[2], adv[3] + vv[3]};
    float4 q1 = {adv[4] + vv[4], adv[5] + vv[5], adv[6] + vv[6], adv[7] + vv[7]};

    *(float4*)(adv_out + base)     = a0;
    *(float4*)(adv_out + base + 4) = a1;
    *(float4*)(ret_out + base)     = q0;
    *(float4*)(ret_out + base + 4) = q1;
}

extern "C" void kernel_launch(void* const* d_in, const int* in_sizes, int n_in,
                              void* d_out, int out_size, void* d_ws, size_t ws_size,
                              hipStream_t stream) {
    const float* reward     = (const float*)d_in[0];
    const int*   terminated = (const int*)  d_in[1];
    const float* value      = (const float*)d_in[2];
    const float* next_value = (const float*)d_in[3];

    const int total = in_sizes[0];          // B * T
    const int B     = total / T_LEN;        // T fixed at 2048 per setup_inputs()

    float* adv = (float*)d_out;             // outputs concatenated: [advantages | returns]
    float* ret = (float*)d_out + (size_t)total;

    gae_kernel<<<B, BLOCK, 0, stream>>>(reward, terminated, value, next_value, adv, ret);
}